// Round 3
// baseline (1215.576 us; speedup 1.0000x reference)
//
#include <hip/hip_runtime.h>
#include <stdint.h>

#define N_    64
#define CIN   128
#define CMID  256
#define H_    56
#define W_    56
#define OH    28
#define OW    28
#define NPIX  (OH*OW)          // 784
#define CNT_CH (N_*NPIX)       // 50176
#define PXW   58               // padded conv1 input dim
#define PYW   30               // padded conv2 input dim
#define EPS_  1e-5f

// ---- stats float indices ----
// 0 sumAbsW1, 1 sumAbsW2, 2 sumAbsWs
// 16 bn1_sum[256], 272 bn1_sq[256], 528 bn2_sum[256], 784 bn2_sq[256]
// 1040 bn2_scale[256], 1296 bn2_off[256], 1552 bn1_A[256], 1808 bn1_B[256]
#define STATS_BYTES 16384
#define OFF_PX  16384                       // u32[64*58*58*4]  = 3,444,736 B (zero-padded)
#define OFF_PY  (OFF_PX + 3444736)          // u32[64*30*30*8]  = 1,843,200 B (zero-padded)
#define OFF_PW1 (OFF_PY + 1843200)          // u32[256*9*4]   = 36,864 B
#define OFF_PW2 (OFF_PW1 + 36864)           // u32[256*9*8]   = 73,728 B
#define OFF_PWS (OFF_PW2 + 73728)           // u32[256*4]     = 4,096 B
#define OFF_E1  (OFF_PWS + 4096)            // int[256*4]     = 4,096 B
#define OFF_E2  (OFF_E1 + 4096)             // int[256*8]     = 8,192 B
#define OFF_Y1  (OFF_E2 + 8192)             // int16[64*256*784] = 25,690,112 B
#define MEMSET_BYTES OFF_PW1                // stats + padded px + padded py start at 0

__global__ __launch_bounds__(256) void reduce_abs_k(const float* __restrict__ w, int n,
                                                    float* __restrict__ out) {
  float s = 0.f;
  for (int i = blockIdx.x * 256 + threadIdx.x; i < n; i += gridDim.x * 256)
    s += fabsf(w[i]);
  for (int off = 32; off; off >>= 1) s += __shfl_down(s, off);
  if ((threadIdx.x & 63) == 0) atomicAdd(out, s);
}

// pack x -> padded [n][58*58][4 words]; pad pre-zeroed by memset
__global__ __launch_bounds__(256) void pack_x_k(const float* __restrict__ x,
                                                uint32_t* __restrict__ px) {
  int idx = blockIdx.x * 256 + threadIdx.x;       // 200704 = 64*3136
  int n = idx / (H_ * W_);
  int hw = idx - n * (H_ * W_);
  int ih = hw / W_, iw = hw - (hw / W_) * W_;
  const float* xp = x + (size_t)n * CIN * H_ * W_ + hw;
  uint32_t wds[4] = {0u, 0u, 0u, 0u};
  for (int c = 0; c < CIN; ++c)
    if (xp[(size_t)c * (H_ * W_)] >= 0.f) wds[c >> 5] |= (1u << (c & 31));
  ((uint4*)px)[(size_t)n * (PXW * PXW) + (ih + 1) * PXW + (iw + 1)] =
      make_uint4(wds[0], wds[1], wds[2], wds[3]);
}

// pw1 layout [o][tap][4 words]
__global__ __launch_bounds__(256) void pack_w1_k(const float* __restrict__ w,
                                                 uint32_t* __restrict__ pw) {
  int idx = blockIdx.x * 256 + threadIdx.x;       // 9216
  int o = idx / 36, r = idx - (idx / 36) * 36;
  int t = r >> 2, word = r & 3;
  uint32_t bits = 0u;
  const float* wp = w + (size_t)o * CIN * 9 + t;
#pragma unroll
  for (int i = 0; i < 32; ++i)
    if (wp[(size_t)(word * 32 + i) * 9] >= 0.f) bits |= (1u << i);
  pw[o * 36 + t * 4 + word] = bits;
}

// pw2 layout [o][tap][8 words]
__global__ __launch_bounds__(256) void pack_w2_k(const float* __restrict__ w,
                                                 uint32_t* __restrict__ pw) {
  int idx = blockIdx.x * 256 + threadIdx.x;       // 18432
  int o = idx / 72, r = idx - (idx / 72) * 72;
  int t = r >> 3, word = r & 7;
  uint32_t bits = 0u;
  const float* wp = w + (size_t)o * CMID * 9 + t;
#pragma unroll
  for (int i = 0; i < 32; ++i)
    if (wp[(size_t)(word * 32 + i) * 9] >= 0.f) bits |= (1u << i);
  pw[o * 72 + t * 8 + word] = bits;
}

// pws layout [o][4 words]
__global__ __launch_bounds__(256) void pack_ws_k(const float* __restrict__ w,
                                                 uint32_t* __restrict__ pw) {
  int idx = blockIdx.x * 256 + threadIdx.x;       // 1024
  int o = idx >> 2, word = idx & 3;
  uint32_t bits = 0u;
  const float* wp = w + (size_t)o * CIN + word * 32;
#pragma unroll
  for (int i = 0; i < 32; ++i)
    if (wp[i] >= 0.f) bits |= (1u << i);
  pw[o * 4 + word] = bits;
}

// per-o zero-pad compensation constants: ct[t] = K - 2*popc(weight tap t)
__global__ void edge_k(const uint32_t* __restrict__ pw1,
                       const uint32_t* __restrict__ pw2,
                       int* __restrict__ e1, int* __restrict__ e2) {
  int o = threadIdx.x;                            // 1 block x 256
  int ct[9];
#pragma unroll
  for (int t = 0; t < 9; ++t) {
    int p = 0;
#pragma unroll
    for (int j = 0; j < 4; ++j) p += __popc(pw1[o * 36 + t * 4 + j]);
    ct[t] = CIN - 2 * p;
  }
  e1[o * 4 + 0] = ct[0] + ct[1] + ct[2];          // top row
  e1[o * 4 + 1] = ct[0] + ct[3] + ct[6];          // left col
  e1[o * 4 + 2] = ct[0];                          // TL corner
  e1[o * 4 + 3] = 0;
#pragma unroll
  for (int t = 0; t < 9; ++t) {
    int p = 0;
#pragma unroll
    for (int j = 0; j < 8; ++j) p += __popc(pw2[o * 72 + t * 8 + j]);
    ct[t] = CMID - 2 * p;
  }
  e2[o * 8 + 0] = ct[0] + ct[1] + ct[2];          // top
  e2[o * 8 + 1] = ct[6] + ct[7] + ct[8];          // bottom
  e2[o * 8 + 2] = ct[0] + ct[3] + ct[6];          // left
  e2[o * 8 + 3] = ct[2] + ct[5] + ct[8];          // right
  e2[o * 8 + 4] = ct[0]; e2[o * 8 + 5] = ct[2];   // corners
  e2[o * 8 + 6] = ct[6]; e2[o * 8 + 7] = ct[8];
}

// conv1: thread = output pixel, o-loop with SGPR weights.
// grid = 196 pixel-blocks x 4 channel-splits
__global__ __launch_bounds__(256, 2) void conv1_k(const uint32_t* __restrict__ px,
                                                  const uint32_t* __restrict__ pw1,
                                                  const int* __restrict__ e1,
                                                  int16_t* __restrict__ y1,
                                                  float* __restrict__ stats) {
  int pb = blockIdx.x >> 2, cs = blockIdx.x & 3;
  int obase = cs * 64;
  int tid = threadIdx.x;
  int gid = pb * 256 + tid;                       // 0..50175
  int n = gid / NPIX, pix = gid - n * NPIX;
  int oh = pix / OW, ow = pix - (pix / OW) * OW;

  uint32_t act[36];
  {
    const uint32_t* ap = px + ((size_t)n * (PXW * PXW) + (2 * oh) * PXW + (2 * ow)) * 4;
#pragma unroll
    for (int kh = 0; kh < 3; ++kh)
#pragma unroll
      for (int kw = 0; kw < 3; ++kw) {
        uint4 a = *(const uint4*)(ap + (kh * PXW + kw) * 4);
        int b = (kh * 3 + kw) * 4;
        act[b] = a.x; act[b + 1] = a.y; act[b + 2] = a.z; act[b + 3] = a.w;
      }
  }
  bool mT = (oh == 0), mL = (ow == 0);
  int16_t* yo = y1 + ((size_t)n * CMID) * NPIX + pix;

  for (int j = 0; j < 64; ++j) {
    int o = obase + j;
    const uint32_t* wp = pw1 + o * 36;
    int p = 0;
#pragma unroll
    for (int t = 0; t < 36; ++t) p += __popc(act[t] ^ wp[t]);
    int corr = (mT ? e1[o * 4 + 0] : 0) + (mL ? e1[o * 4 + 1] : 0)
             - ((mT && mL) ? e1[o * 4 + 2] : 0);
    int d = 9 * CIN - 2 * p - corr;
    yo[(size_t)o * NPIX] = (int16_t)d;
    float f = (float)d;
    float s = f, q = f * f;
    for (int off = 32; off; off >>= 1) { s += __shfl_down(s, off); q += __shfl_down(q, off); }
    if ((tid & 63) == 0) { atomicAdd(&stats[16 + o], s); atomicAdd(&stats[272 + o], q); }
  }
}

// BN1 coefficient prep (A applied to raw int dot, B offset)
__global__ void bn1_prep_k(float* __restrict__ stats,
                           const float* __restrict__ g1,
                           const float* __restrict__ b1) {
  int c = threadIdx.x;                            // 1 block x 256
  float alpha1 = stats[0] * (1.f / (CMID * CIN * 9));
  float S = stats[16 + c], S2 = stats[272 + c];
  float mu = alpha1 * (S * (1.f / CNT_CH));
  float ey2 = alpha1 * alpha1 * (S2 * (1.f / CNT_CH));
  float var = fmaxf(ey2 - mu * mu, 0.f);
  float rs = rsqrtf(var + EPS_);
  float g = g1[c];
  stats[1552 + c] = g * rs * alpha1;
  stats[1808 + c] = b1[c] - g * rs * mu;
}

// BN1 + sign + pack -> padded py. thread = pixel, loops 64 channels.
// grid = 196 pixel-blocks x 4 channel-quarters
__global__ __launch_bounds__(256) void pack_y_k(const int16_t* __restrict__ y1,
                                                const float* __restrict__ stats,
                                                uint32_t* __restrict__ py) {
  int pb = blockIdx.x >> 2, q = blockIdx.x & 3;
  int tid = threadIdx.x;
  int gid = pb * 256 + tid;
  int n = gid / NPIX, pix = gid - n * NPIX;
  int oh = pix / OW, ow = pix - (pix / OW) * OW;
  const int16_t* yp = y1 + ((size_t)n * CMID + q * 64) * NPIX + pix;
  const float* A = stats + 1552 + q * 64;
  const float* B = stats + 1808 + q * 64;
  uint32_t w0 = 0u, w1 = 0u;
#pragma unroll
  for (int i = 0; i < 32; ++i) {
    int v = yp[(size_t)i * NPIX];
    if (fmaf(A[i], (float)v, B[i]) >= 0.f) w0 |= (1u << i);
  }
#pragma unroll
  for (int i = 0; i < 32; ++i) {
    int v = yp[(size_t)(32 + i) * NPIX];
    if (fmaf(A[32 + i], (float)v, B[32 + i]) >= 0.f) w1 |= (1u << i);
  }
  size_t off = ((size_t)n * (PYW * PYW) + (oh + 1) * PYW + (ow + 1)) * 8 + q * 2;
  *(uint2*)(py + off) = make_uint2(w0, w1);
}

// conv2 + shortcut: thread = output pixel, o-loop with SGPR weights.
__global__ __launch_bounds__(256, 2) void conv2_k(const uint32_t* __restrict__ py,
                                                  const uint32_t* __restrict__ pw2,
                                                  const uint32_t* __restrict__ px,
                                                  const uint32_t* __restrict__ pws,
                                                  const int* __restrict__ e2,
                                                  const float* __restrict__ stats,
                                                  float* __restrict__ y2,
                                                  float* __restrict__ statw) {
  int pb = blockIdx.x >> 2, cs = blockIdx.x & 3;
  int obase = cs * 64;
  int tid = threadIdx.x;
  int gid = pb * 256 + tid;
  int n = gid / NPIX, pix = gid - n * NPIX;
  int oh = pix / OW, ow = pix - (pix / OW) * OW;

  uint32_t act[72];
  {
    const uint32_t* ap = py + ((size_t)n * (PYW * PYW) + oh * PYW + ow) * 8;
#pragma unroll
    for (int kh = 0; kh < 3; ++kh)
#pragma unroll
      for (int kw = 0; kw < 3; ++kw) {
        const uint32_t* t = ap + (kh * PYW + kw) * 8;
        uint4 a0 = *(const uint4*)t, a1 = *(const uint4*)(t + 4);
        int b = (kh * 3 + kw) * 8;
        act[b] = a0.x; act[b + 1] = a0.y; act[b + 2] = a0.z; act[b + 3] = a0.w;
        act[b + 4] = a1.x; act[b + 5] = a1.y; act[b + 6] = a1.z; act[b + 7] = a1.w;
      }
  }
  uint4 ax = *(const uint4*)(px + ((size_t)n * (PXW * PXW) + (2 * oh + 1) * PXW + (2 * ow + 1)) * 4);
  bool mT = (oh == 0), mB = (oh == OH - 1), mL = (ow == 0), mR = (ow == OW - 1);
  float alpha2 = stats[1] * (1.f / (CMID * CMID * 9));
  float alphas = stats[2] * (1.f / (CMID * CIN));
  float* yo = y2 + ((size_t)n * CMID) * NPIX + pix;

  for (int j = 0; j < 64; ++j) {
    int o = obase + j;
    const uint32_t* wp = pw2 + o * 72;
    int p = 0;
#pragma unroll
    for (int t = 0; t < 72; ++t) p += __popc(act[t] ^ wp[t]);
    const int* e = e2 + o * 8;
    int corr = (mT ? e[0] : 0) + (mB ? e[1] : 0) + (mL ? e[2] : 0) + (mR ? e[3] : 0)
             - ((mT && mL) ? e[4] : 0) - ((mT && mR) ? e[5] : 0)
             - ((mB && mL) ? e[6] : 0) - ((mB && mR) ? e[7] : 0);
    int d = 9 * CMID - 2 * p - corr;
    const uint32_t* sp = pws + o * 4;
    int ps = __popc(ax.x ^ sp[0]) + __popc(ax.y ^ sp[1]) +
             __popc(ax.z ^ sp[2]) + __popc(ax.w ^ sp[3]);
    float val = alpha2 * (float)d + alphas * (float)(CIN - 2 * ps);
    yo[(size_t)o * NPIX] = val;
    float s = val, q = val * val;
    for (int off = 32; off; off >>= 1) { s += __shfl_down(s, off); q += __shfl_down(q, off); }
    if ((tid & 63) == 0) { atomicAdd(&statw[528 + o], s); atomicAdd(&statw[784 + o], q); }
  }
}

__global__ void bn2_prep_k(float* __restrict__ stats,
                           const float* __restrict__ g2,
                           const float* __restrict__ b2) {
  int c = threadIdx.x;                            // 1 block x 256
  float S = stats[528 + c], S2 = stats[784 + c];
  float mu = S * (1.f / CNT_CH);
  float var = fmaxf(S2 * (1.f / CNT_CH) - mu * mu, 0.f);
  float rs = rsqrtf(var + EPS_);
  float g = g2[c];
  stats[1040 + c] = g * rs;
  stats[1296 + c] = b2[c] - g * rs * mu;
}

__global__ __launch_bounds__(256) void bn2_apply_k(float4* __restrict__ out,
                                                   const float* __restrict__ stats) {
  int idx = blockIdx.x * 256 + threadIdx.x;       // 3,211,264 float4s = 12544 blocks
  int c = (idx / (NPIX / 4)) & (CMID - 1);
  float sc = stats[1040 + c], of = stats[1296 + c];
  float4 v = out[idx];
  v.x = v.x * sc + of; v.y = v.y * sc + of; v.z = v.z * sc + of; v.w = v.w * sc + of;
  out[idx] = v;
}

extern "C" void kernel_launch(void* const* d_in, const int* in_sizes, int n_in,
                              void* d_out, int out_size, void* d_ws, size_t ws_size,
                              hipStream_t stream) {
  const float* x   = (const float*)d_in[0];
  const float* w1  = (const float*)d_in[1];
  const float* g1  = (const float*)d_in[2];
  const float* b1  = (const float*)d_in[3];
  const float* w2  = (const float*)d_in[4];
  const float* g2  = (const float*)d_in[5];
  const float* b2  = (const float*)d_in[6];
  const float* wsc = (const float*)d_in[7];
  float* out = (float*)d_out;

  char* ws = (char*)d_ws;
  float*    stats = (float*)ws;
  uint32_t* px  = (uint32_t*)(ws + OFF_PX);
  uint32_t* py  = (uint32_t*)(ws + OFF_PY);
  uint32_t* pw1 = (uint32_t*)(ws + OFF_PW1);
  uint32_t* pw2 = (uint32_t*)(ws + OFF_PW2);
  uint32_t* pws = (uint32_t*)(ws + OFF_PWS);
  int*      e1  = (int*)(ws + OFF_E1);
  int*      e2  = (int*)(ws + OFF_E2);
  int16_t*  y1  = (int16_t*)(ws + OFF_Y1);

  hipMemsetAsync(ws, 0, MEMSET_BYTES, stream);    // stats + padded px + padded py

  reduce_abs_k<<<128, 256, 0, stream>>>(w1,  CMID * CIN * 9,  &stats[0]);
  reduce_abs_k<<<256, 256, 0, stream>>>(w2,  CMID * CMID * 9, &stats[1]);
  reduce_abs_k<<<32,  256, 0, stream>>>(wsc, CMID * CIN,      &stats[2]);

  pack_x_k<<<784, 256, 0, stream>>>(x, px);
  pack_w1_k<<<36, 256, 0, stream>>>(w1, pw1);
  pack_w2_k<<<72, 256, 0, stream>>>(w2, pw2);
  pack_ws_k<<<4, 256, 0, stream>>>(wsc, pws);
  edge_k<<<1, 256, 0, stream>>>(pw1, pw2, e1, e2);

  conv1_k<<<784, 256, 0, stream>>>(px, pw1, e1, y1, stats);
  bn1_prep_k<<<1, 256, 0, stream>>>(stats, g1, b1);
  pack_y_k<<<784, 256, 0, stream>>>(y1, stats, py);
  conv2_k<<<784, 256, 0, stream>>>(py, pw2, px, pws, e2, stats, out, stats);
  bn2_prep_k<<<1, 256, 0, stream>>>(stats, g2, b2);
  bn2_apply_k<<<12544, 256, 0, stream>>>((float4*)out, stats);
}

// Round 4
// 457.378 us; speedup vs baseline: 2.6577x; 2.6577x over previous
//
#include <hip/hip_runtime.h>
#include <stdint.h>

#define N_    64
#define CIN   128
#define CMID  256
#define H_    56
#define W_    56
#define OH    28
#define OW    28
#define NPIX  (OH*OW)          // 784
#define MPAD  800              // per-image M padded to 25*32
#define MTOT  (N_*MPAD)        // 51200
#define CNT_CH (N_*NPIX)       // 50176
#define PXH   58               // padded conv1 input spatial
#define PYH   30               // padded conv2 input spatial
#define EPS_  1e-5f

// ---- stats float indices ----
// 0 sumAbsW1, 1 sumAbsW2, 2 sumAbsWs
// 16 bn1_sum[256], 272 bn1_sq[256], 528 bn2_sum[256], 784 bn2_sq[256]
// 1040 bn2_scale[256], 1296 bn2_off[256], 1552 bn1_A[256], 1808 bn1_B[256]
#define STATS_BYTES 16384
#define OFF_PXI 16384                         // i8 [64][58][58][128] = 27,551,744
#define OFF_PYI (OFF_PXI + 27551744)          // i8 [64][30][30][256] = 14,745,600
#define OFF_W1F (OFF_PYI + 14745600)          // 36*8*1024 = 294,912
#define OFF_W2F (OFF_W1F + 294912)            // 72*8*1024 = 589,824
#define OFF_WSF (OFF_W2F + 589824)            // 4*8*1024  = 32,768
#define MEMSET_BYTES OFF_W1F                  // stats + px + py zeroed
// total ws = 43,231,232 B;  y16 (int16 [50176][256] = 25.7 MB) lives in d_out

typedef int v4i  __attribute__((ext_vector_type(4)));
typedef int v16i __attribute__((ext_vector_type(16)));

__global__ __launch_bounds__(256) void reduce_abs_k(const float* __restrict__ w, int n,
                                                    float* __restrict__ out) {
  float s = 0.f;
  for (int i = blockIdx.x * 256 + threadIdx.x; i < n; i += gridDim.x * 256)
    s += fabsf(w[i]);
  for (int off = 32; off; off >>= 1) s += __shfl_down(s, off);
  if ((threadIdx.x & 63) == 0) atomicAdd(out, s);
}

// x NCHW f32 -> sign i8 NHWC zero-padded [n][58][58][128]
__global__ __launch_bounds__(256) void pack_x_k(const float* __restrict__ x,
                                                int8_t* __restrict__ px) {
  int idx = blockIdx.x * 256 + threadIdx.x;       // 200704
  int n = idx / (H_ * W_), hw = idx - n * (H_ * W_);
  int ih = hw / W_, iw = hw - ih * W_;
  const float* xp = x + ((size_t)n * CIN) * (H_ * W_) + hw;
  uint32_t wd[32];
#pragma unroll
  for (int c4 = 0; c4 < 32; ++c4) {
    uint32_t wv = 0u;
#pragma unroll
    for (int j = 0; j < 4; ++j) {
      uint32_t b = (xp[(size_t)(c4 * 4 + j) * (H_ * W_)] >= 0.f) ? 0x01u : 0xFFu;
      wv |= b << (j * 8);
    }
    wd[c4] = wv;
  }
  uint4* dst = (uint4*)(px + (((size_t)n * (PXH * PXH) + (ih + 1) * PXH + (iw + 1)) * CIN));
#pragma unroll
  for (int q = 0; q < 8; ++q)
    dst[q] = make_uint4(wd[q * 4], wd[q * 4 + 1], wd[q * 4 + 2], wd[q * 4 + 3]);
}

// weight sign bytes pre-packed in MFMA B-fragment order:
// frag (kc, nb): lane l byte j = sign(W[k = kc*32 + (l>>5)*16 + j][o = nb*32 + (l&31)])
__global__ __launch_bounds__(256) void packw1f_k(const float* __restrict__ w1,
                                                 uint32_t* __restrict__ w1f) {
  int T = blockIdx.x * 256 + threadIdx.x;         // 18432 = 36*8*64
  int l = T & 63, fb = T >> 6;
  int nb = fb & 7, kc = fb >> 3;
  int o = nb * 32 + (l & 31);
  int kbase = kc * 32 + (l >> 5) * 16;
  uint32_t wd[4] = {0u, 0u, 0u, 0u};
#pragma unroll
  for (int j = 0; j < 16; ++j) {
    int k = kbase + j, t = k >> 7, c = k & 127;
    uint32_t b = (w1[((size_t)o * CIN + c) * 9 + t] >= 0.f) ? 0x01u : 0xFFu;
    wd[j >> 2] |= b << ((j & 3) * 8);
  }
  ((uint4*)w1f)[T] = make_uint4(wd[0], wd[1], wd[2], wd[3]);
}

__global__ __launch_bounds__(256) void packw2f_k(const float* __restrict__ w2,
                                                 uint32_t* __restrict__ w2f) {
  int T = blockIdx.x * 256 + threadIdx.x;         // 36864 = 72*8*64
  int l = T & 63, fb = T >> 6;
  int nb = fb & 7, kc = fb >> 3;
  int o = nb * 32 + (l & 31);
  int kbase = kc * 32 + (l >> 5) * 16;
  uint32_t wd[4] = {0u, 0u, 0u, 0u};
#pragma unroll
  for (int j = 0; j < 16; ++j) {
    int k = kbase + j, t = k >> 8, c = k & 255;
    uint32_t b = (w2[((size_t)o * CMID + c) * 9 + t] >= 0.f) ? 0x01u : 0xFFu;
    wd[j >> 2] |= b << ((j & 3) * 8);
  }
  ((uint4*)w2f)[T] = make_uint4(wd[0], wd[1], wd[2], wd[3]);
}

__global__ __launch_bounds__(256) void packwsf_k(const float* __restrict__ ws,
                                                 uint32_t* __restrict__ wsf) {
  int T = blockIdx.x * 256 + threadIdx.x;         // 2048 = 4*8*64
  int l = T & 63, fb = T >> 6;
  int nb = fb & 7, kc = fb >> 3;
  int o = nb * 32 + (l & 31);
  int kbase = kc * 32 + (l >> 5) * 16;
  uint32_t wd[4] = {0u, 0u, 0u, 0u};
#pragma unroll
  for (int j = 0; j < 16; ++j) {
    int c = kbase + j;
    uint32_t b = (ws[(size_t)o * CIN + c] >= 0.f) ? 0x01u : 0xFFu;
    wd[j >> 2] |= b << ((j & 3) * 8);
  }
  ((uint4*)wsf)[T] = make_uint4(wd[0], wd[1], wd[2], wd[3]);
}

// conv1: implicit GEMM, M=51200 (padded pixels), N=256, K=9*128.
// block = 4 waves; wave = 64 px x 64 out. Writes raw dots int16 -> y16 (d_out).
__global__ __launch_bounds__(256, 4) void conv1_k(const int8_t* __restrict__ px,
                                                  const uint8_t* __restrict__ w1f,
                                                  short* __restrict__ y16,
                                                  float* __restrict__ stats) {
  int bnh = blockIdx.x & 1, bm = blockIdx.x >> 1;  // 800 blocks
  int tid = threadIdx.x, w = tid >> 6, l = tid & 63;
  int l31 = l & 31, lhi = l >> 5;
  int waveM = bm * 128 + (w & 1) * 64;
  int waveN = bnh * 128 + (w >> 1) * 64;
  int nbg = waveN >> 5;

  const int8_t* abase[2];
#pragma unroll
  for (int m = 0; m < 2; ++m) {
    int pix = waveM + m * 32 + l31;
    int n = pix / MPAD, hw = pix - n * MPAD;
    int oh = hw / OW, ow = hw - oh * OW;
    abase[m] = px + (((size_t)n * (PXH * PXH) + (2 * oh) * PXH + 2 * ow) * CIN + lhi * 16);
  }
  const uint8_t* wb = w1f + (size_t)l * 16;
  v16i acc[2][2] = {};

  for (int t = 0; t < 9; ++t) {
    int kh = t / 3, kw = t - 3 * kh;
    int aoff = (kh * PXH + kw) * CIN;
#pragma unroll
    for (int cc = 0; cc < 4; ++cc) {
      int kc = t * 4 + cc;
      v4i a0 = *(const v4i*)(abase[0] + aoff + cc * 32);
      v4i a1 = *(const v4i*)(abase[1] + aoff + cc * 32);
      v4i b0 = *(const v4i*)(wb + (size_t)(kc * 8 + nbg) * 1024);
      v4i b1 = *(const v4i*)(wb + (size_t)(kc * 8 + nbg + 1) * 1024);
      acc[0][0] = __builtin_amdgcn_mfma_i32_32x32x32_i8(a0, b0, acc[0][0], 0, 0, 0);
      acc[0][1] = __builtin_amdgcn_mfma_i32_32x32x32_i8(a0, b1, acc[0][1], 0, 0, 0);
      acc[1][0] = __builtin_amdgcn_mfma_i32_32x32x32_i8(a1, b0, acc[1][0], 0, 0, 0);
      acc[1][1] = __builtin_amdgcn_mfma_i32_32x32x32_i8(a1, b1, acc[1][1], 0, 0, 0);
    }
  }
#pragma unroll
  for (int n2 = 0; n2 < 2; ++n2) {
    int o = waveN + n2 * 32 + l31;
    float ssum = 0.f, ssq = 0.f;
#pragma unroll
    for (int m = 0; m < 2; ++m) {
      int tbase = waveM + m * 32;
      int nb0 = tbase / MPAD, r0 = tbase - nb0 * MPAD;   // 32-aligned: never crosses image
#pragma unroll
      for (int r = 0; r < 16; ++r) {
        int row = (r & 3) + 8 * (r >> 2) + 4 * lhi;
        int hwr = r0 + row;
        int d = acc[m][n2][r];
        bool valid = hwr < NPIX;
        if (valid) y16[((size_t)nb0 * NPIX + hwr) * CMID + o] = (short)d;
        float fd = valid ? (float)d : 0.f;
        ssum += fd; ssq += fd * fd;
      }
    }
    ssum += __shfl_down(ssum, 32);
    ssq  += __shfl_down(ssq, 32);
    if (l < 32) { atomicAdd(&stats[16 + o], ssum); atomicAdd(&stats[272 + o], ssq); }
  }
}

__global__ void bn1_prep_k(float* __restrict__ stats,
                           const float* __restrict__ g1,
                           const float* __restrict__ b1) {
  int c = threadIdx.x;                            // 1 x 256
  float alpha1 = stats[0] * (1.f / (CMID * CIN * 9));
  float S = stats[16 + c], S2 = stats[272 + c];
  float mu = alpha1 * (S * (1.f / CNT_CH));
  float ey2 = alpha1 * alpha1 * (S2 * (1.f / CNT_CH));
  float var = fmaxf(ey2 - mu * mu, 0.f);
  float rs = rsqrtf(var + EPS_);
  float g = g1[c];
  stats[1552 + c] = g * rs * alpha1;
  stats[1808 + c] = b1[c] - g * rs * mu;
}

// BN1 + sign -> py i8 NHWC padded [n][30][30][256]
__global__ __launch_bounds__(256) void pack_y_k(const short* __restrict__ y16,
                                                const float* __restrict__ stats,
                                                int8_t* __restrict__ py) {
  int gid = blockIdx.x * 256 + threadIdx.x;       // 1,605,632 = 6272*256
  int cg = gid & 31, pix = gid >> 5;
  int n = pix / NPIX, hw = pix - n * NPIX;
  int oh = hw / OW, ow = hw - oh * OW;
  uint4 raw = *(const uint4*)(y16 + (size_t)pix * CMID + cg * 8);
  const float* A = stats + 1552 + cg * 8;
  const float* B = stats + 1808 + cg * 8;
  float4 A0 = *(const float4*)A, A1 = *(const float4*)(A + 4);
  float4 B0 = *(const float4*)B, B1 = *(const float4*)(B + 4);
  int s[8];
  s[0] = (int)(short)(raw.x & 0xFFFF); s[1] = ((int)raw.x) >> 16;
  s[2] = (int)(short)(raw.y & 0xFFFF); s[3] = ((int)raw.y) >> 16;
  s[4] = (int)(short)(raw.z & 0xFFFF); s[5] = ((int)raw.z) >> 16;
  s[6] = (int)(short)(raw.w & 0xFFFF); s[7] = ((int)raw.w) >> 16;
  float a[8] = {A0.x, A0.y, A0.z, A0.w, A1.x, A1.y, A1.z, A1.w};
  float b[8] = {B0.x, B0.y, B0.z, B0.w, B1.x, B1.y, B1.z, B1.w};
  uint32_t w0 = 0u, w1 = 0u;
#pragma unroll
  for (int j = 0; j < 4; ++j) {
    w0 |= ((fmaf(a[j], (float)s[j], b[j]) >= 0.f) ? 0x01u : 0xFFu) << (j * 8);
    w1 |= ((fmaf(a[4 + j], (float)s[4 + j], b[4 + j]) >= 0.f) ? 0x01u : 0xFFu) << (j * 8);
  }
  size_t off = ((size_t)n * (PYH * PYH) + (oh + 1) * PYH + (ow + 1)) * CMID + cg * 8;
  *(uint2*)(py + off) = make_uint2(w0, w1);
}

// conv2 + fused 1x1 shortcut: M=51200, N=256, K=9*256 (+128 shortcut)
__global__ __launch_bounds__(256, 2) void conv2_k(const int8_t* __restrict__ py,
                                                  const int8_t* __restrict__ px,
                                                  const uint8_t* __restrict__ w2f,
                                                  const uint8_t* __restrict__ wsf,
                                                  const float* __restrict__ stats,
                                                  float* __restrict__ out,
                                                  float* __restrict__ statw) {
  int bnh = blockIdx.x & 1, bm = blockIdx.x >> 1;  // 800 blocks
  int tid = threadIdx.x, w = tid >> 6, l = tid & 63;
  int l31 = l & 31, lhi = l >> 5;
  int waveM = bm * 128 + (w & 1) * 64;
  int waveN = bnh * 128 + (w >> 1) * 64;
  int nbg = waveN >> 5;

  const int8_t* abase[2];
  const int8_t* sbase[2];
#pragma unroll
  for (int m = 0; m < 2; ++m) {
    int pix = waveM + m * 32 + l31;
    int n = pix / MPAD, hw = pix - n * MPAD;
    int oh = hw / OW, ow = hw - oh * OW;
    abase[m] = py + (((size_t)n * (PYH * PYH) + oh * PYH + ow) * CMID + lhi * 16);
    sbase[m] = px + (((size_t)n * (PXH * PXH) + (2 * oh + 1) * PXH + (2 * ow + 1)) * CIN + lhi * 16);
  }
  const uint8_t* wb = w2f + (size_t)l * 16;
  const uint8_t* sb = wsf + (size_t)l * 16;
  v16i am[2][2] = {};
  v16i as[2][2] = {};

  for (int t = 0; t < 9; ++t) {
    int kh = t / 3, kw = t - 3 * kh;
    int aoff = (kh * PYH + kw) * CMID;
#pragma unroll
    for (int cc = 0; cc < 8; ++cc) {
      int kc = t * 8 + cc;
      v4i a0 = *(const v4i*)(abase[0] + aoff + cc * 32);
      v4i a1 = *(const v4i*)(abase[1] + aoff + cc * 32);
      v4i b0 = *(const v4i*)(wb + (size_t)(kc * 8 + nbg) * 1024);
      v4i b1 = *(const v4i*)(wb + (size_t)(kc * 8 + nbg + 1) * 1024);
      am[0][0] = __builtin_amdgcn_mfma_i32_32x32x32_i8(a0, b0, am[0][0], 0, 0, 0);
      am[0][1] = __builtin_amdgcn_mfma_i32_32x32x32_i8(a0, b1, am[0][1], 0, 0, 0);
      am[1][0] = __builtin_amdgcn_mfma_i32_32x32x32_i8(a1, b0, am[1][0], 0, 0, 0);
      am[1][1] = __builtin_amdgcn_mfma_i32_32x32x32_i8(a1, b1, am[1][1], 0, 0, 0);
    }
  }
#pragma unroll
  for (int cc = 0; cc < 4; ++cc) {
    v4i a0 = *(const v4i*)(sbase[0] + cc * 32);
    v4i a1 = *(const v4i*)(sbase[1] + cc * 32);
    v4i b0 = *(const v4i*)(sb + (size_t)(cc * 8 + nbg) * 1024);
    v4i b1 = *(const v4i*)(sb + (size_t)(cc * 8 + nbg + 1) * 1024);
    as[0][0] = __builtin_amdgcn_mfma_i32_32x32x32_i8(a0, b0, as[0][0], 0, 0, 0);
    as[0][1] = __builtin_amdgcn_mfma_i32_32x32x32_i8(a0, b1, as[0][1], 0, 0, 0);
    as[1][0] = __builtin_amdgcn_mfma_i32_32x32x32_i8(a1, b0, as[1][0], 0, 0, 0);
    as[1][1] = __builtin_amdgcn_mfma_i32_32x32x32_i8(a1, b1, as[1][1], 0, 0, 0);
  }

  float a2  = stats[1] * (1.f / (CMID * CMID * 9));
  float asx = stats[2] * (1.f / (CMID * CIN));
#pragma unroll
  for (int n2 = 0; n2 < 2; ++n2) {
    int o = waveN + n2 * 32 + l31;
    float ssum = 0.f, ssq = 0.f;
#pragma unroll
    for (int m = 0; m < 2; ++m) {
      int tbase = waveM + m * 32;
      int nb0 = tbase / MPAD, r0 = tbase - nb0 * MPAD;
#pragma unroll
      for (int r = 0; r < 16; ++r) {
        int row = (r & 3) + 8 * (r >> 2) + 4 * lhi;
        int hwr = r0 + row;
        bool valid = hwr < NPIX;
        float v = a2 * (float)am[m][n2][r] + asx * (float)as[m][n2][r];
        if (valid) out[((size_t)nb0 * CMID + o) * NPIX + hwr] = v;
        float vm = valid ? v : 0.f;
        ssum += vm; ssq += vm * vm;
      }
    }
    ssum += __shfl_down(ssum, 32);
    ssq  += __shfl_down(ssq, 32);
    if (l < 32) { atomicAdd(&statw[528 + o], ssum); atomicAdd(&statw[784 + o], ssq); }
  }
}

__global__ void bn2_prep_k(float* __restrict__ stats,
                           const float* __restrict__ g2,
                           const float* __restrict__ b2) {
  int c = threadIdx.x;                            // 1 x 256
  float S = stats[528 + c], S2 = stats[784 + c];
  float mu = S * (1.f / CNT_CH);
  float var = fmaxf(S2 * (1.f / CNT_CH) - mu * mu, 0.f);
  float rs = rsqrtf(var + EPS_);
  float g = g2[c];
  stats[1040 + c] = g * rs;
  stats[1296 + c] = b2[c] - g * rs * mu;
}

__global__ __launch_bounds__(256) void bn2_apply_k(float4* __restrict__ out,
                                                   const float* __restrict__ stats) {
  int idx = blockIdx.x * 256 + threadIdx.x;       // 3,211,264 float4s = 12544 blocks
  int c = (idx / (NPIX / 4)) & (CMID - 1);
  float sc = stats[1040 + c], of = stats[1296 + c];
  float4 v = out[idx];
  v.x = v.x * sc + of; v.y = v.y * sc + of; v.z = v.z * sc + of; v.w = v.w * sc + of;
  out[idx] = v;
}

extern "C" void kernel_launch(void* const* d_in, const int* in_sizes, int n_in,
                              void* d_out, int out_size, void* d_ws, size_t ws_size,
                              hipStream_t stream) {
  const float* x   = (const float*)d_in[0];
  const float* w1  = (const float*)d_in[1];
  const float* g1  = (const float*)d_in[2];
  const float* b1  = (const float*)d_in[3];
  const float* w2  = (const float*)d_in[4];
  const float* g2  = (const float*)d_in[5];
  const float* b2  = (const float*)d_in[6];
  const float* wsc = (const float*)d_in[7];
  float* out = (float*)d_out;

  char* ws = (char*)d_ws;
  float*    stats = (float*)ws;
  int8_t*   pxi = (int8_t*)(ws + OFF_PXI);
  int8_t*   pyi = (int8_t*)(ws + OFF_PYI);
  uint32_t* w1f = (uint32_t*)(ws + OFF_W1F);
  uint32_t* w2f = (uint32_t*)(ws + OFF_W2F);
  uint32_t* wsf = (uint32_t*)(ws + OFF_WSF);
  short*    y16 = (short*)d_out;                  // conv1 raw dots, dead after pack_y

  hipMemsetAsync(ws, 0, MEMSET_BYTES, stream);    // stats + padded px + padded py

  reduce_abs_k<<<128, 256, 0, stream>>>(w1,  CMID * CIN * 9,  &stats[0]);
  reduce_abs_k<<<256, 256, 0, stream>>>(w2,  CMID * CMID * 9, &stats[1]);
  reduce_abs_k<<<32,  256, 0, stream>>>(wsc, CMID * CIN,      &stats[2]);

  pack_x_k<<<784, 256, 0, stream>>>(x, pxi);
  packw1f_k<<<72, 256, 0, stream>>>(w1, w1f);
  packw2f_k<<<144, 256, 0, stream>>>(w2, w2f);
  packwsf_k<<<8, 256, 0, stream>>>(wsc, wsf);

  conv1_k<<<800, 256, 0, stream>>>(pxi, (const uint8_t*)w1f, y16, stats);
  bn1_prep_k<<<1, 256, 0, stream>>>(stats, g1, b1);
  pack_y_k<<<6272, 256, 0, stream>>>(y16, stats, pyi);
  conv2_k<<<800, 256, 0, stream>>>(pyi, pxi, (const uint8_t*)w2f, (const uint8_t*)wsf,
                                   stats, out, stats);
  bn2_prep_k<<<1, 256, 0, stream>>>(stats, g2, b2);
  bn2_apply_k<<<12544, 256, 0, stream>>>((float4*)out, stats);
}